// Round 1
// baseline (2270.076 us; speedup 1.0000x reference)
//
#include <hip/hip_runtime.h>

typedef _Float16 half_t;
typedef _Float16 half2_t __attribute__((ext_vector_type(2)));

#define T_STEPS 256
#define F_IN    32
#define HDIM    64
#define NB      16          // batches per block
#define NBLOCKS (4096/NB)   // 256 blocks

__device__ inline unsigned int pack2(float a, float b) {
    half2_t h;
    h.x = (_Float16)a;
    h.y = (_Float16)b;
    return __builtin_bit_cast(unsigned int, h);
}

__device__ inline float fdot2_u(unsigned int a, unsigned int b, float c) {
    half2_t ha = __builtin_bit_cast(half2_t, a);
    half2_t hb = __builtin_bit_cast(half2_t, b);
#if __has_builtin(__builtin_amdgcn_fdot2)
    return __builtin_amdgcn_fdot2(ha, hb, c, false);
#else
    return c + (float)ha.x * (float)hb.x + (float)ha.y * (float)hb.y;
#endif
}

__device__ inline float fast_sigmoid(float z) {
    return 1.0f / (1.0f + __expf(-z));
}
__device__ inline float fast_tanh(float z) {
    // 1 - 2/(e^{2z}+1); exact at +/-inf, ~1e-7 abs err
    return 1.0f - 2.0f / (__expf(2.0f * z) + 1.0f);
}

// LDS:
//  W0p[48][256] : layer1 weights, f16x2 along k. k2<16 -> W_ih0 (x), k2>=16 -> W_hh0 (h1)
//  W1p[64][256] : layer2 weights. k2<32 -> W_ih1 (h1), k2>=32 -> W_hh1 (h2)
//  A0 [48][18]  : layer1 A operand per batch: k2<16 x_t pairs, 16+u2 h1 pairs   (pad 18 for 8B align)
//  A1 [64][18]  : layer2 A operand: u2<32 h1 pairs, 32+u2 h2 pairs
__global__ __launch_bounds__(256, 1)
void lstm_fused(const float* __restrict__ x,
                const float* __restrict__ Wih0, const float* __restrict__ Whh0,
                const float* __restrict__ bih0, const float* __restrict__ bhh0,
                const float* __restrict__ Wih1, const float* __restrict__ Whh1,
                const float* __restrict__ bih1, const float* __restrict__ bhh1,
                const float* __restrict__ Wout, const float* __restrict__ bout,
                float* __restrict__ out)
{
    __shared__ unsigned int W0p[48][256];
    __shared__ unsigned int W1p[64][256];
    __shared__ unsigned int A0[48][18];
    __shared__ unsigned int A1[64][18];

    const int tid = threadIdx.x;
    const int gb0 = blockIdx.x * NB;

    // ---- stage weights to LDS as f16 pairs (thread g owns gate row g) ----
    {
        const int g = tid;
        #pragma unroll 4
        for (int k2 = 0; k2 < 16; ++k2) {
            float2 w = *(const float2*)(Wih0 + g * F_IN + 2 * k2);
            W0p[k2][g] = pack2(w.x, w.y);
        }
        #pragma unroll 4
        for (int k2 = 0; k2 < 32; ++k2) {
            float2 w = *(const float2*)(Whh0 + g * HDIM + 2 * k2);
            W0p[16 + k2][g] = pack2(w.x, w.y);
        }
        #pragma unroll 4
        for (int k2 = 0; k2 < 32; ++k2) {
            float2 w = *(const float2*)(Wih1 + g * HDIM + 2 * k2);
            W1p[k2][g] = pack2(w.x, w.y);
        }
        #pragma unroll 4
        for (int k2 = 0; k2 < 32; ++k2) {
            float2 w = *(const float2*)(Whh1 + g * HDIM + 2 * k2);
            W1p[32 + k2][g] = pack2(w.x, w.y);
        }
    }
    // zero the A buffers (h states start at 0)
    for (int i = tid; i < 48 * 18; i += 256) ((unsigned int*)A0)[i] = 0u;
    for (int i = tid; i < 64 * 18; i += 256) ((unsigned int*)A1)[i] = 0u;

    // ---- per-thread ownership ----
    const int bq = tid >> 5;    // 0..7  -> batches 2bq, 2bq+1 (local)
    const int uq = tid & 31;    // 0..31 -> units 2uq, 2uq+1

    // biases held in registers (gate = 64*q + 2*uq + p)
    float b0r[4][2], b1r[4][2];
    #pragma unroll
    for (int q = 0; q < 4; ++q)
        #pragma unroll
        for (int p = 0; p < 2; ++p) {
            const int g = 64 * q + 2 * uq + p;
            b0r[q][p] = bih0[g] + bhh0[g];
            b1r[q][p] = bih1[g] + bhh1[g];
        }

    float c1[2][2] = {{0.f, 0.f}, {0.f, 0.f}};
    float c2[2][2] = {{0.f, 0.f}, {0.f, 0.f}};

    // staging map: thread -> (sb = tid/16 batch, sd = tid%16 feature pair)
    const int sb = tid >> 4, sd = tid & 15;
    const float* xrow = x + (long)(gb0 + sb) * T_STEPS * F_IN + 2 * sd;

    __syncthreads();   // weights + zeroed state visible

    for (int t = 0; t < T_STEPS; ++t) {
        // ---- stage x_t (f16 pairs, transposed) ----
        {
            const float2 xv = *(const float2*)(xrow + t * F_IN);
            A0[sd][sb] = pack2(xv.x, xv.y);
        }
        __syncthreads();   // (1) x staged, h1/h2 from prev step visible

        // ---- GEMM1: gates1 = [x_t | h1] @ W0^T + bias ----
        float acc[2][4][2];
        #pragma unroll
        for (int q = 0; q < 4; ++q)
            #pragma unroll
            for (int p = 0; p < 2; ++p) {
                acc[0][q][p] = b0r[q][p];
                acc[1][q][p] = b0r[q][p];
            }
        #pragma unroll 4
        for (int k2 = 0; k2 < 48; ++k2) {
            const uint2 a = *(const uint2*)&A0[k2][2 * bq];
            const unsigned int av[2] = {a.x, a.y};
            #pragma unroll
            for (int q = 0; q < 4; ++q) {
                const uint2 w = *(const uint2*)&W0p[k2][64 * q + 2 * uq];
                const unsigned int wv[2] = {w.x, w.y};
                #pragma unroll
                for (int i = 0; i < 2; ++i)
                    #pragma unroll
                    for (int p = 0; p < 2; ++p)
                        acc[i][q][p] = fdot2_u(av[i], wv[p], acc[i][q][p]);
            }
        }

        // ---- activations layer 1 (gate order: i,f,g,o) ----
        float hn[2][2];
        #pragma unroll
        for (int i = 0; i < 2; ++i)
            #pragma unroll
            for (int p = 0; p < 2; ++p) {
                const float ig = fast_sigmoid(acc[i][0][p]);
                const float fg = fast_sigmoid(acc[i][1][p]);
                const float gg = fast_tanh(acc[i][2][p]);
                const float og = fast_sigmoid(acc[i][3][p]);
                const float c = fg * c1[i][p] + ig * gg;
                c1[i][p] = c;
                hn[i][p] = og * fast_tanh(c);
            }
        __syncthreads();   // (2) all GEMM1 reads of old h1 complete
        #pragma unroll
        for (int i = 0; i < 2; ++i) {
            const unsigned int hp = pack2(hn[i][0], hn[i][1]);
            A0[16 + uq][2 * bq + i] = hp;   // for next step's layer-1 GEMM
            A1[uq][2 * bq + i] = hp;        // for this step's layer-2 GEMM
        }
        __syncthreads();   // (3) new h1 visible

        // ---- GEMM2: gates2 = [h1 | h2] @ W1^T + bias ----
        #pragma unroll
        for (int q = 0; q < 4; ++q)
            #pragma unroll
            for (int p = 0; p < 2; ++p) {
                acc[0][q][p] = b1r[q][p];
                acc[1][q][p] = b1r[q][p];
            }
        #pragma unroll 4
        for (int k2 = 0; k2 < 64; ++k2) {
            const uint2 a = *(const uint2*)&A1[k2][2 * bq];
            const unsigned int av[2] = {a.x, a.y};
            #pragma unroll
            for (int q = 0; q < 4; ++q) {
                const uint2 w = *(const uint2*)&W1p[k2][64 * q + 2 * uq];
                const unsigned int wv[2] = {w.x, w.y};
                #pragma unroll
                for (int i = 0; i < 2; ++i)
                    #pragma unroll
                    for (int p = 0; p < 2; ++p)
                        acc[i][q][p] = fdot2_u(av[i], wv[p], acc[i][q][p]);
            }
        }

        // ---- activations layer 2 ----
        #pragma unroll
        for (int i = 0; i < 2; ++i)
            #pragma unroll
            for (int p = 0; p < 2; ++p) {
                const float ig = fast_sigmoid(acc[i][0][p]);
                const float fg = fast_sigmoid(acc[i][1][p]);
                const float gg = fast_tanh(acc[i][2][p]);
                const float og = fast_sigmoid(acc[i][3][p]);
                const float c = fg * c2[i][p] + ig * gg;
                c2[i][p] = c;
                hn[i][p] = og * fast_tanh(c);
            }
        __syncthreads();   // (4) all GEMM2 reads of old h2 complete
        #pragma unroll
        for (int i = 0; i < 2; ++i)
            A1[32 + uq][2 * bq + i] = pack2(hn[i][0], hn[i][1]);
        // next iteration's x-staging touches A0 x-part only; no conflict with A1 h2 writes
    }

    __syncthreads();   // final h2 visible

    // ---- output head: out[b] = h2_last . W_out + b_out ----
    if (tid < NB) {
        float s = bout[0];
        #pragma unroll 8
        for (int j = 0; j < 32; ++j) {
            const half2_t h = __builtin_bit_cast(half2_t, A1[32 + j][tid]);
            s += (float)h.x * Wout[2 * j] + (float)h.y * Wout[2 * j + 1];
        }
        out[gb0 + tid] = s;
    }
}

extern "C" void kernel_launch(void* const* d_in, const int* in_sizes, int n_in,
                              void* d_out, int out_size, void* d_ws, size_t ws_size,
                              hipStream_t stream) {
    const float* x    = (const float*)d_in[0];
    const float* Wih0 = (const float*)d_in[1];
    const float* Whh0 = (const float*)d_in[2];
    const float* bih0 = (const float*)d_in[3];
    const float* bhh0 = (const float*)d_in[4];
    const float* Wih1 = (const float*)d_in[5];
    const float* Whh1 = (const float*)d_in[6];
    const float* bih1 = (const float*)d_in[7];
    const float* bhh1 = (const float*)d_in[8];
    const float* Wout = (const float*)d_in[9];
    const float* bout = (const float*)d_in[10];

    hipLaunchKernelGGL(lstm_fused, dim3(NBLOCKS), dim3(256), 0, stream,
                       x, Wih0, Whh0, bih0, bhh0,
                       Wih1, Whh1, bih1, bhh1, Wout, bout,
                       (float*)d_out);
}

// Round 2
// 262.914 us; speedup vs baseline: 8.6343x; 8.6343x over previous
//
#include <hip/hip_runtime.h>

typedef _Float16 half8 __attribute__((ext_vector_type(8)));
typedef _Float16 half4 __attribute__((ext_vector_type(4)));
typedef _Float16 half2_t __attribute__((ext_vector_type(2)));
typedef float f32x4 __attribute__((ext_vector_type(4)));

#define T_STEPS 256
#define NB      16           // batches per block
#define NBLOCKS (4096/NB)    // 256 blocks = 1 per CU

__device__ inline unsigned int pack2(float a, float b) {
    half2_t h;
    h.x = (_Float16)a;
    h.y = (_Float16)b;
    return __builtin_bit_cast(unsigned int, h);
}

// sigmoid(z) = 1/(1+2^(-z*log2e)) ; tanh(z) = 1 - 2/(2^(2z*log2e)+1)
__device__ inline float sigmoid_f(float z) {
    return __builtin_amdgcn_rcpf(1.0f + __builtin_amdgcn_exp2f(-1.4426950408889634f * z));
}
__device__ inline float tanh_f(float z) {
    return 1.0f - 2.0f * __builtin_amdgcn_rcpf(1.0f + __builtin_amdgcn_exp2f(2.8853900817779268f * z));
}

// load 8 consecutive f32, convert to f16x8
__device__ inline half8 cvt8(const float* __restrict__ p) {
    half8 r;
    #pragma unroll
    for (int j = 0; j < 8; ++j) r[j] = (_Float16)p[j];
    return r;
}

// LDS activation operands, batch-major (row n = batch, col = k), double buffered:
//  A1[p][n][0..31]  = x_t          A1[p][n][32..95]  = h1      (pad to 104)
//  A2[p][n][0..63]  = h1           A2[p][n][64..127] = h2      (pad to 136)
// B-fragment for mfma_f32_16x16x32_f16: lane l -> col n=l&15, k = 32*ks + 8*(l>>4) + j
// A-fragment (weights, VGPR-resident): lane l -> row m=l&15, same k map -> contraction
// is correct for any HW k-permutation shared by A and B.
__global__ __launch_bounds__(256, 1)
void lstm_mfma(const float* __restrict__ x,
               const float* __restrict__ Wih0, const float* __restrict__ Whh0,
               const float* __restrict__ bih0, const float* __restrict__ bhh0,
               const float* __restrict__ Wih1, const float* __restrict__ Whh1,
               const float* __restrict__ bih1, const float* __restrict__ bhh1,
               const float* __restrict__ Wout, const float* __restrict__ bout,
               float* __restrict__ out)
{
    __shared__ _Float16 A1[2][16][104];
    __shared__ _Float16 A2[2][16][136];

    const int tid = threadIdx.x;
    const int w   = tid >> 6;      // wave 0..3
    const int l   = tid & 63;
    const int ln  = l & 15;        // A row (gate) / B col (batch)
    const int lb  = l >> 4;        // k block 0..3
    const int u0  = 16 * w + 4 * lb;   // first unit this lane's acc covers
    const int gb0 = blockIdx.x * NB;

    // ---- one-time: weight A-fragments into VGPRs ----
    // wave w, gate-type q -> M-tile m0 = w + 4q -> gates g = 64q + 16w + ln
    half8 wa1[4][3], wa2[4][4];
    #pragma unroll
    for (int q = 0; q < 4; ++q) {
        const int g = 64 * q + 16 * w + ln;
        #pragma unroll
        for (int ks = 0; ks < 3; ++ks) {
            const int c0 = 32 * ks + 8 * lb;        // k in [0,96): <32 -> x-part, else h-part
            const float* p = (c0 < 32) ? (Wih0 + g * 32 + c0)
                                       : (Whh0 + g * 64 + (c0 - 32));
            wa1[q][ks] = cvt8(p);
        }
        #pragma unroll
        for (int ks = 0; ks < 4; ++ks) {
            const int c0 = 32 * ks + 8 * lb;        // k in [0,128): <64 -> h1-part, else h2-part
            const float* p = (c0 < 64) ? (Wih1 + g * 64 + c0)
                                       : (Whh1 + g * 64 + (c0 - 64));
            wa2[q][ks] = cvt8(p);
        }
    }

    // biases as f32x4 (acc-reg j -> gate 64q + u0 + j)
    f32x4 bv1[4], bv2[4];
    #pragma unroll
    for (int q = 0; q < 4; ++q)
        #pragma unroll
        for (int j = 0; j < 4; ++j) {
            const int g = 64 * q + u0 + j;
            bv1[q][j] = bih0[g] + bhh0[g];
            bv2[q][j] = bih1[g] + bhh1[g];
        }

    // ---- zero LDS (h states start at 0) ----
    for (int i = tid; i < 2 * 16 * 104; i += 256) ((_Float16*)A1)[i] = (_Float16)0.f;
    for (int i = tid; i < 2 * 16 * 136; i += 256) ((_Float16*)A2)[i] = (_Float16)0.f;

    // x staging map: thread -> (batch sb, f32-pair sd)
    const int sb = tid >> 4, sd = tid & 15;
    const float* xptr = x + (long)(gb0 + sb) * T_STEPS * 32 + 2 * sd;
    float2 xv = *(const float2*)xptr;   // t = 0

    float c1[4] = {0.f, 0.f, 0.f, 0.f};
    float c2[4] = {0.f, 0.f, 0.f, 0.f};

    __syncthreads();   // zeroed LDS visible before first x-stage

    for (int t = 0; t < T_STEPS; ++t) {
        const int p = t & 1;

        // ---- stage x_t (f16 pairs, batch-major), prefetch x_{t+1} ----
        *(unsigned int*)&A1[p][sb][2 * sd] = pack2(xv.x, xv.y);
        if (t + 1 < T_STEPS) xv = *(const float2*)(xptr + (t + 1) * 32);
        __syncthreads();   // (alpha) x_t + h1(t-1) + h2(t-1) visible

        // ---- layer 1: G1 = W0 @ [x_t ; h1] ----
        half8 bf[4];
        #pragma unroll
        for (int ks = 0; ks < 3; ++ks)
            bf[ks] = *(const half8*)&A1[p][ln][32 * ks + 8 * lb];

        f32x4 acc[4];
        #pragma unroll
        for (int q = 0; q < 4; ++q) {
            acc[q] = bv1[q];
            #pragma unroll
            for (int ks = 0; ks < 3; ++ks)
                acc[q] = __builtin_amdgcn_mfma_f32_16x16x32_f16(wa1[q][ks], bf[ks], acc[q], 0, 0, 0);
        }

        // ---- cell update layer 1 (gate order i,f,g,o) ----
        half4 h1h;
        #pragma unroll
        for (int j = 0; j < 4; ++j) {
            const float ig = sigmoid_f(acc[0][j]);
            const float fg = sigmoid_f(acc[1][j]);
            const float gg = tanh_f(acc[2][j]);
            const float og = sigmoid_f(acc[3][j]);
            const float c  = fg * c1[j] + ig * gg;
            c1[j] = c;
            h1h[j] = (_Float16)(og * tanh_f(c));
        }
        // h1 -> next step's layer1 operand (other buffer) + this step's layer2 operand
        *(half4*)&A1[p ^ 1][ln][32 + u0] = h1h;
        *(half4*)&A2[p][ln][u0] = h1h;
        __syncthreads();   // (beta) new h1 visible

        // ---- layer 2: G2 = W1 @ [h1 ; h2] ----
        #pragma unroll
        for (int ks = 0; ks < 4; ++ks)
            bf[ks] = *(const half8*)&A2[p][ln][32 * ks + 8 * lb];

        #pragma unroll
        for (int q = 0; q < 4; ++q) {
            acc[q] = bv2[q];
            #pragma unroll
            for (int ks = 0; ks < 4; ++ks)
                acc[q] = __builtin_amdgcn_mfma_f32_16x16x32_f16(wa2[q][ks], bf[ks], acc[q], 0, 0, 0);
        }

        // ---- cell update layer 2 ----
        half4 h2h;
        #pragma unroll
        for (int j = 0; j < 4; ++j) {
            const float ig = sigmoid_f(acc[0][j]);
            const float fg = sigmoid_f(acc[1][j]);
            const float gg = tanh_f(acc[2][j]);
            const float og = sigmoid_f(acc[3][j]);
            const float c  = fg * c2[j] + ig * gg;
            c2[j] = c;
            h2h[j] = (_Float16)(og * tanh_f(c));
        }
        *(half4*)&A2[p ^ 1][ln][64 + u0] = h2h;   // h2 -> next step (other buffer)
    }

    __syncthreads();   // final h2 (in A2[0], since t=255 wrote p^1=0) visible

    // ---- output head: out[b] = h2_last . Wout + bout ----
    if (tid < NB) {
        float s = bout[0];
        #pragma unroll 8
        for (int u = 0; u < 64; ++u)
            s += (float)A2[0][tid][64 + u] * Wout[u];
        out[gb0 + tid] = s;
    }
}

extern "C" void kernel_launch(void* const* d_in, const int* in_sizes, int n_in,
                              void* d_out, int out_size, void* d_ws, size_t ws_size,
                              hipStream_t stream) {
    const float* x    = (const float*)d_in[0];
    const float* Wih0 = (const float*)d_in[1];
    const float* Whh0 = (const float*)d_in[2];
    const float* bih0 = (const float*)d_in[3];
    const float* bhh0 = (const float*)d_in[4];
    const float* Wih1 = (const float*)d_in[5];
    const float* Whh1 = (const float*)d_in[6];
    const float* bih1 = (const float*)d_in[7];
    const float* bhh1 = (const float*)d_in[8];
    const float* Wout = (const float*)d_in[9];
    const float* bout = (const float*)d_in[10];

    hipLaunchKernelGGL(lstm_mfma, dim3(NBLOCKS), dim3(256), 0, stream,
                       x, Wih0, Whh0, bih0, bhh0,
                       Wih1, Whh1, bih1, bhh1, Wout, bout,
                       (float*)d_out);
}

// Round 3
// 224.937 us; speedup vs baseline: 10.0920x; 1.1688x over previous
//
#include <hip/hip_runtime.h>

typedef _Float16 half8 __attribute__((ext_vector_type(8)));
typedef _Float16 half4 __attribute__((ext_vector_type(4)));
typedef float f32x4 __attribute__((ext_vector_type(4)));

#define T_STEPS 256
#define NB      16
#define NBLOCKS (4096/NB)
#define LOG2E   1.4426950408889634f

// LDS row strides (f16 units), chosen so b128 B-fragment reads are
// bank-conflict-free: stride 104 -> (13*ln+lb)%8 permutation, stride 152 ->
// (3*ln+lb)%8 permutation over each consecutive lane octet.
#define S1 104   // A1: k 0..31 = x_t, 32..95 = h1
#define S2 152   // A2: k 0..63 = h1,  64..127 = h2

// load 8 consecutive f32, scale by log2e, convert to f16x8
__device__ __forceinline__ half8 cvt8s(const float* __restrict__ p) {
    half8 r;
    #pragma unroll
    for (int j = 0; j < 8; ++j) r[j] = (_Float16)(p[j] * LOG2E);
    return r;
}

__global__ __launch_bounds__(256, 1)
void lstm_pipe(const float* __restrict__ x,
               const float* __restrict__ Wih0, const float* __restrict__ Whh0,
               const float* __restrict__ bih0, const float* __restrict__ bhh0,
               const float* __restrict__ Wih1, const float* __restrict__ Whh1,
               const float* __restrict__ bih1, const float* __restrict__ bhh1,
               const float* __restrict__ Wout, const float* __restrict__ bout,
               float* __restrict__ out)
{
    __shared__ _Float16 A1[2][16][S1];
    __shared__ _Float16 A2[2][16][S2];

    const int tid = threadIdx.x;
    const int w   = tid >> 6;
    const bool g1 = (w < 2);           // waves 0,1 = layer 1; waves 2,3 = layer 2
    const int wl  = g1 ? w : (w - 2);  // wave index within group
    const int l   = tid & 63;
    const int ln  = l & 15;            // A row (weight row) / B col (batch)
    const int lb  = l >> 4;            // k sub-block / C-row group
    const int gb0 = blockIdx.x * NB;

    // ---- weight A-fragments (VGPR resident, pre-scaled by log2e) ----
    // group-1 wave wl, gate-type q, unit-group ug -> gates 64q + 32wl + 16ug + (0..15)
    half8 wa[4][2][4];
    f32x4 bv[4][2];
    if (g1) {
        #pragma unroll
        for (int q = 0; q < 4; ++q)
            #pragma unroll
            for (int ug = 0; ug < 2; ++ug) {
                const int g = 64 * q + 32 * wl + 16 * ug + ln;
                #pragma unroll
                for (int ks = 0; ks < 3; ++ks) {
                    const int c0 = 32 * ks + 8 * lb;   // k in [0,96)
                    const float* p = (c0 < 32) ? (Wih0 + g * 32 + c0)
                                               : (Whh0 + g * 64 + (c0 - 32));
                    wa[q][ug][ks] = cvt8s(p);
                }
                #pragma unroll
                for (int jj = 0; jj < 4; ++jj) {
                    const int gj = 64 * q + 32 * wl + 16 * ug + 4 * lb + jj;
                    bv[q][ug][jj] = (bih0[gj] + bhh0[gj]) * LOG2E;
                }
            }
    } else {
        #pragma unroll
        for (int q = 0; q < 4; ++q)
            #pragma unroll
            for (int ug = 0; ug < 2; ++ug) {
                const int g = 64 * q + 32 * wl + 16 * ug + ln;
                #pragma unroll
                for (int ks = 0; ks < 4; ++ks) {
                    const int c0 = 32 * ks + 8 * lb;   // k in [0,128)
                    const float* p = (c0 < 64) ? (Wih1 + g * 64 + c0)
                                               : (Whh1 + g * 64 + (c0 - 64));
                    wa[q][ug][ks] = cvt8s(p);
                }
                #pragma unroll
                for (int jj = 0; jj < 4; ++jj) {
                    const int gj = 64 * q + 32 * wl + 16 * ug + 4 * lb + jj;
                    bv[q][ug][jj] = (bih1[gj] + bhh1[gj]) * LOG2E;
                }
            }
    }

    float cst[2][4];      // cell state: c1 for group-1 waves, c2 for group-2 waves
    #pragma unroll
    for (int ug = 0; ug < 2; ++ug)
        #pragma unroll
        for (int jj = 0; jj < 4; ++jj) cst[ug][jj] = 0.f;

    // ---- zero LDS ----
    {
        unsigned int* z = (unsigned int*)A1;
        for (int i = tid; i < (int)(sizeof(A1) / 4); i += 256) z[i] = 0u;
        unsigned int* z2 = (unsigned int*)A2;
        for (int i = tid; i < (int)(sizeof(A2) / 4); i += 256) z2[i] = 0u;
    }
    __syncthreads();

    // ---- x staging (group-1 threads: tid<128): thread -> batch tid>>3, cols 4*(tid&7).. ----
    const int sbx = tid >> 3, sdx = tid & 7;
    const float* xbase = x + (long)(gb0 + sbx) * T_STEPS * 32 + 4 * sdx;
    float4 xv = {0.f, 0.f, 0.f, 0.f};
    if (g1) {
        const float4 x0 = *(const float4*)xbase;
        half4 hx;
        hx[0] = (_Float16)x0.x; hx[1] = (_Float16)x0.y;
        hx[2] = (_Float16)x0.z; hx[3] = (_Float16)x0.w;
        *(half4*)&A1[0][sbx][4 * sdx] = hx;      // x_0
        xv = *(const float4*)(xbase + 32);       // x_1
    }
    __syncthreads();

#define ACTIVATE(ACC, UG, JJ, HH)                                              \
    {                                                                          \
        const float si = ACC[0][UG][JJ];                                       \
        const float sf = ACC[1][UG][JJ];                                       \
        const float sg = ACC[2][UG][JJ];                                       \
        const float so = ACC[3][UG][JJ];                                       \
        const float ei = __builtin_amdgcn_exp2f(-si);                          \
        const float ef = __builtin_amdgcn_exp2f(-sf);                          \
        const float Eg = __builtin_amdgcn_exp2f(sg + sg);                      \
        const float eo = __builtin_amdgcn_exp2f(-so);                          \
        const float sigf = __builtin_amdgcn_rcpf(1.f + ef);                    \
        const float rig  = __builtin_amdgcn_rcpf((1.f + ei) * (1.f + Eg));     \
        const float c    = sigf * cst[UG][JJ] + (Eg - 1.f) * rig;              \
        cst[UG][JJ] = c;                                                       \
        const float Ec  = __builtin_amdgcn_exp2f(fminf((2.f * LOG2E) * c, 120.f)); \
        const float roc = __builtin_amdgcn_rcpf((1.f + eo) * (1.f + Ec));      \
        HH[JJ] = (_Float16)((Ec - 1.f) * roc);                                 \
    }

#define STEP(J, P)                                                             \
    do {                                                                       \
        if (g1 && (J) < T_STEPS) {                                             \
            /* write x_{J+1} into next buffer, prefetch x_{J+2} */             \
            if ((J) < T_STEPS - 1) {                                           \
                half4 hx;                                                      \
                hx[0] = (_Float16)xv.x; hx[1] = (_Float16)xv.y;                \
                hx[2] = (_Float16)xv.z; hx[3] = (_Float16)xv.w;                \
                *(half4*)&A1[1 - (P)][sbx][4 * sdx] = hx;                      \
            }                                                                  \
            if ((J) < T_STEPS - 2) xv = *(const float4*)(xbase + ((J) + 2) * 32); \
            /* layer 1: gates = W0' @ [x_J ; h1(J-1)] */                       \
            half8 bf0 = *(const half8*)&A1[P][ln][8 * lb];                     \
            half8 bf1 = *(const half8*)&A1[P][ln][32 + 8 * lb];                \
            half8 bf2 = *(const half8*)&A1[P][ln][64 + 8 * lb];                \
            f32x4 acc[4][2];                                                   \
            _Pragma("unroll")                                                  \
            for (int q = 0; q < 4; ++q)                                        \
                _Pragma("unroll")                                              \
                for (int ug = 0; ug < 2; ++ug) {                               \
                    acc[q][ug] = bv[q][ug];                                    \
                    acc[q][ug] = __builtin_amdgcn_mfma_f32_16x16x32_f16(wa[q][ug][0], bf0, acc[q][ug], 0, 0, 0); \
                    acc[q][ug] = __builtin_amdgcn_mfma_f32_16x16x32_f16(wa[q][ug][1], bf1, acc[q][ug], 0, 0, 0); \
                    acc[q][ug] = __builtin_amdgcn_mfma_f32_16x16x32_f16(wa[q][ug][2], bf2, acc[q][ug], 0, 0, 0); \
                }                                                              \
            _Pragma("unroll")                                                  \
            for (int ug = 0; ug < 2; ++ug) {                                   \
                half4 hh;                                                      \
                ACTIVATE(acc, ug, 0, hh); ACTIVATE(acc, ug, 1, hh);            \
                ACTIVATE(acc, ug, 2, hh); ACTIVATE(acc, ug, 3, hh);            \
                const int ubase = 32 * wl + 16 * ug + 4 * lb;                  \
                *(half4*)&A1[1 - (P)][ln][32 + ubase] = hh;                    \
                *(half4*)&A2[1 - (P)][ln][ubase] = hh;                         \
            }                                                                  \
        }                                                                      \
        if (!g1 && (J) > 0) {                                                  \
            /* layer 2 (one step behind): gates = W1' @ [h1(J-1) ; h2(J-2)] */ \
            half8 cf0 = *(const half8*)&A2[P][ln][8 * lb];                     \
            half8 cf1 = *(const half8*)&A2[P][ln][32 + 8 * lb];                \
            half8 cf2 = *(const half8*)&A2[P][ln][64 + 8 * lb];                \
            half8 cf3 = *(const half8*)&A2[P][ln][96 + 8 * lb];                \
            f32x4 acc[4][2];                                                   \
            _Pragma("unroll")                                                  \
            for (int q = 0; q < 4; ++q)                                        \
                _Pragma("unroll")                                              \
                for (int ug = 0; ug < 2; ++ug) {                               \
                    acc[q][ug] = bv[q][ug];                                    \
                    acc[q][ug] = __builtin_amdgcn_mfma_f32_16x16x32_f16(wa[q][ug][0], cf0, acc[q][ug], 0, 0, 0); \
                    acc[q][ug] = __builtin_amdgcn_mfma_f32_16x16x32_f16(wa[q][ug][1], cf1, acc[q][ug], 0, 0, 0); \
                    acc[q][ug] = __builtin_amdgcn_mfma_f32_16x16x32_f16(wa[q][ug][2], cf2, acc[q][ug], 0, 0, 0); \
                    acc[q][ug] = __builtin_amdgcn_mfma_f32_16x16x32_f16(wa[q][ug][3], cf3, acc[q][ug], 0, 0, 0); \
                }                                                              \
            _Pragma("unroll")                                                  \
            for (int ug = 0; ug < 2; ++ug) {                                   \
                half4 hh;                                                      \
                ACTIVATE(acc, ug, 0, hh); ACTIVATE(acc, ug, 1, hh);            \
                ACTIVATE(acc, ug, 2, hh); ACTIVATE(acc, ug, 3, hh);            \
                const int ubase = 32 * wl + 16 * ug + 4 * lb;                  \
                *(half4*)&A2[1 - (P)][ln][64 + ubase] = hh;                    \
            }                                                                  \
        }                                                                      \
        __syncthreads();                                                       \
    } while (0)

    for (int jj = 0; jj < T_STEPS; jj += 2) {
        STEP(jj, 0);
        STEP(jj + 1, 1);
    }
    STEP(T_STEPS, 0);   // drain: layer-2 computes h2(255) -> A2[1]

    // ---- output head: out[b] = h2(255) . Wout + bout ----
    if (tid < NB) {
        float s = bout[0];
        #pragma unroll 8
        for (int u = 0; u < 64; ++u)
            s += (float)A2[1][tid][64 + u] * Wout[u];
        out[gb0 + tid] = s;
    }
}

extern "C" void kernel_launch(void* const* d_in, const int* in_sizes, int n_in,
                              void* d_out, int out_size, void* d_ws, size_t ws_size,
                              hipStream_t stream) {
    const float* x    = (const float*)d_in[0];
    const float* Wih0 = (const float*)d_in[1];
    const float* Whh0 = (const float*)d_in[2];
    const float* bih0 = (const float*)d_in[3];
    const float* bhh0 = (const float*)d_in[4];
    const float* Wih1 = (const float*)d_in[5];
    const float* Whh1 = (const float*)d_in[6];
    const float* bih1 = (const float*)d_in[7];
    const float* bhh1 = (const float*)d_in[8];
    const float* Wout = (const float*)d_in[9];
    const float* bout = (const float*)d_in[10];

    hipLaunchKernelGGL(lstm_pipe, dim3(NBLOCKS), dim3(256), 0, stream,
                       x, Wih0, Whh0, bih0, bhh0,
                       Wih1, Whh1, bih1, bhh1, Wout, bout,
                       (float*)d_out);
}

// Round 4
// 184.918 us; speedup vs baseline: 12.2761x; 1.2164x over previous
//
#include <hip/hip_runtime.h>

typedef _Float16 half8 __attribute__((ext_vector_type(8)));
typedef _Float16 half4 __attribute__((ext_vector_type(4)));
typedef _Float16 half2_t __attribute__((ext_vector_type(2)));
typedef float f32x4 __attribute__((ext_vector_type(4)));

#define T_STEPS 256
#define NB      16
#define NBLOCKS (4096/NB)
#define LOG2E   1.4426950408889634f

// LDS row strides (f16 units): b128 B-fragment reads are bank-conflict-free
// (stride 104 -> (13*ln+lb)%8 permutation, stride 152 -> (3*ln+lb)%8).
#define S1 104   // A1: k 0..31 = x_t, 32..95 = h1
#define S2 152   // A2: k 0..63 = h1,  64..127 = h2

__device__ __forceinline__ unsigned int pack2(float a, float b) {
    half2_t h;
    h.x = (_Float16)a;
    h.y = (_Float16)b;
    return __builtin_bit_cast(unsigned int, h);
}

// load 8 consecutive f32, scale by log2e, convert to f16x8
__device__ __forceinline__ half8 cvt8s(const float* __restrict__ p) {
    half8 r;
    #pragma unroll
    for (int j = 0; j < 8; ++j) r[j] = (_Float16)(p[j] * LOG2E);
    return r;
}

// raw barrier: LDS ordering only — does NOT drain vmcnt, so global x prefetch
// stays in flight across steps (vs __syncthreads' implicit vmcnt(0) drain).
__device__ __forceinline__ void sync_lds() {
    asm volatile("s_waitcnt lgkmcnt(0)" ::: "memory");
    __builtin_amdgcn_s_barrier();
}

__global__ __launch_bounds__(512, 1)
void lstm_pipe8(const float* __restrict__ x,
                const float* __restrict__ Wih0, const float* __restrict__ Whh0,
                const float* __restrict__ bih0, const float* __restrict__ bhh0,
                const float* __restrict__ Wih1, const float* __restrict__ Whh1,
                const float* __restrict__ bih1, const float* __restrict__ bhh1,
                const float* __restrict__ Wout, const float* __restrict__ bout,
                float* __restrict__ out)
{
    __shared__ _Float16 A1[2][16][S1];
    __shared__ _Float16 A2[2][16][S2];

    const int tid  = threadIdx.x;
    const int w    = tid >> 6;
    const bool isL1 = (w < 4);          // waves 0-3: layer 1; waves 4-7: layer 2
    const int wq   = w & 3;             // wave index within its group
    const int l    = tid & 63;
    const int ln   = l & 15;            // weight row (A) / batch col (B)
    const int lb   = l >> 4;            // k sub-block / C-row group
    const int ub   = 16 * wq + 4 * lb;  // first unit this lane's acc covers
    const int gb0  = blockIdx.x * NB;

    // ---- weight A-fragments, VGPR-resident (48 regs L1 / 64 regs L2 — no spill) ----
    // wave wq, gate-type q -> M-tile gates 64q + 16wq + (0..15)
    half8 wa[4][4];
    f32x4 bv[4];
    if (isL1) {
        #pragma unroll
        for (int q = 0; q < 4; ++q) {
            const int g = 64 * q + 16 * wq + ln;
            #pragma unroll
            for (int ks = 0; ks < 3; ++ks) {
                const int c0 = 32 * ks + 8 * lb;          // k in [0,96)
                const float* p = (c0 < 32) ? (Wih0 + g * 32 + c0)
                                           : (Whh0 + g * 64 + (c0 - 32));
                wa[q][ks] = cvt8s(p);
            }
            #pragma unroll
            for (int jj = 0; jj < 4; ++jj) {
                const int gj = 64 * q + ub + jj;
                bv[q][jj] = (bih0[gj] + bhh0[gj]) * LOG2E;
            }
        }
    } else {
        #pragma unroll
        for (int q = 0; q < 4; ++q) {
            const int g = 64 * q + 16 * wq + ln;
            #pragma unroll
            for (int ks = 0; ks < 4; ++ks) {
                const int c0 = 32 * ks + 8 * lb;          // k in [0,128)
                const float* p = (c0 < 64) ? (Wih1 + g * 64 + c0)
                                           : (Whh1 + g * 64 + (c0 - 64));
                wa[q][ks] = cvt8s(p);
            }
            #pragma unroll
            for (int jj = 0; jj < 4; ++jj) {
                const int gj = 64 * q + ub + jj;
                bv[q][jj] = (bih1[gj] + bhh1[gj]) * LOG2E;
            }
        }
    }

    float cst[4] = {0.f, 0.f, 0.f, 0.f};

    // ---- zero LDS (h/c state starts at 0) ----
    {
        unsigned int* z = (unsigned int*)A1;
        for (int i = tid; i < (int)(sizeof(A1) / 4); i += 512) z[i] = 0u;
        unsigned int* z2 = (unsigned int*)A2;
        for (int i = tid; i < (int)(sizeof(A2) / 4); i += 512) z2[i] = 0u;
    }
    sync_lds();

    // ---- x staging: L1 threads (tid<256) -> batch tid>>4, f32-pair tid&15 ----
    const int sbx = tid >> 4, sdx = tid & 15;
    const float* xbase = x + (long)(gb0 + sbx) * T_STEPS * 32 + 2 * sdx;
    float2 xva = {0.f, 0.f}, xvb = {0.f, 0.f};
    if (isL1) {
        const float2 x0 = *(const float2*)xbase;
        *(unsigned int*)&A1[0][sbx][2 * sdx] = pack2(x0.x, x0.y);  // x_0
        xva = *(const float2*)(xbase + 32);                        // x_1
        xvb = *(const float2*)(xbase + 64);                        // x_2
    }
    sync_lds();

// merged-rcp LSTM cell update: 5 exp2 + 2 rcp per unit. Inputs pre-scaled by log2e.
#define ACT(JJ)                                                                \
    {                                                                          \
        const float si = acc[0][JJ], sf = acc[1][JJ];                          \
        const float sg = acc[2][JJ], so = acc[3][JJ];                          \
        const float ei = __builtin_amdgcn_exp2f(-si);                          \
        const float ef = __builtin_amdgcn_exp2f(-sf);                          \
        const float Eg = __builtin_amdgcn_exp2f(sg + sg);                      \
        const float eo = __builtin_amdgcn_exp2f(-so);                          \
        const float ti = 1.f + ei, tf = 1.f + ef, tg = 1.f + Eg;               \
        const float pig = ti * tg;                                             \
        const float num = cst[JJ] * pig + (Eg - 1.f) * tf;                     \
        const float c   = num * __builtin_amdgcn_rcpf(pig * tf);               \
        cst[JJ] = c;                                                           \
        const float Ec  = __builtin_amdgcn_exp2f(fminf((2.f * LOG2E) * c, 120.f)); \
        hh[JJ] = (_Float16)((Ec - 1.f) *                                       \
                 __builtin_amdgcn_rcpf((1.f + eo) * (1.f + Ec)));              \
    }

#define STEP(J, P)                                                             \
    do {                                                                       \
        if (isL1 && (J) < T_STEPS) {                                           \
            /* stage x_{J+1} into next buffer; prefetch x_{J+3} (3-deep) */    \
            if ((J) < T_STEPS - 1)                                             \
                *(unsigned int*)&A1[1 - (P)][sbx][2 * sdx] = pack2(xva.x, xva.y); \
            xva = xvb;                                                         \
            if ((J) + 3 < T_STEPS) xvb = *(const float2*)(xbase + ((J) + 3) * 32); \
            /* layer 1: gates = W0' @ [x_J ; h1(J-1)] */                       \
            const half8 bf0 = *(const half8*)&A1[P][ln][8 * lb];               \
            const half8 bf1 = *(const half8*)&A1[P][ln][32 + 8 * lb];          \
            const half8 bf2 = *(const half8*)&A1[P][ln][64 + 8 * lb];          \
            f32x4 acc[4];                                                      \
            _Pragma("unroll")                                                  \
            for (int q = 0; q < 4; ++q) {                                      \
                acc[q] = bv[q];                                                \
                acc[q] = __builtin_amdgcn_mfma_f32_16x16x32_f16(wa[q][0], bf0, acc[q], 0, 0, 0); \
                acc[q] = __builtin_amdgcn_mfma_f32_16x16x32_f16(wa[q][1], bf1, acc[q], 0, 0, 0); \
                acc[q] = __builtin_amdgcn_mfma_f32_16x16x32_f16(wa[q][2], bf2, acc[q], 0, 0, 0); \
            }                                                                  \
            half4 hh;                                                          \
            ACT(0) ACT(1) ACT(2) ACT(3)                                        \
            *(half4*)&A1[1 - (P)][ln][32 + ub] = hh;                           \
            *(half4*)&A2[1 - (P)][ln][ub] = hh;                                \
        }                                                                      \
        if (!isL1 && (J) > 0) {                                                \
            /* layer 2 (one step behind): gates = W1' @ [h1(J-1) ; h2(J-2)] */ \
            const half8 bf0 = *(const half8*)&A2[P][ln][8 * lb];               \
            const half8 bf1 = *(const half8*)&A2[P][ln][32 + 8 * lb];          \
            const half8 bf2 = *(const half8*)&A2[P][ln][64 + 8 * lb];          \
            const half8 bf3 = *(const half8*)&A2[P][ln][96 + 8 * lb];          \
            f32x4 acc[4];                                                      \
            _Pragma("unroll")                                                  \
            for (int q = 0; q < 4; ++q) {                                      \
                acc[q] = bv[q];                                                \
                acc[q] = __builtin_amdgcn_mfma_f32_16x16x32_f16(wa[q][0], bf0, acc[q], 0, 0, 0); \
                acc[q] = __builtin_amdgcn_mfma_f32_16x16x32_f16(wa[q][1], bf1, acc[q], 0, 0, 0); \
                acc[q] = __builtin_amdgcn_mfma_f32_16x16x32_f16(wa[q][2], bf2, acc[q], 0, 0, 0); \
                acc[q] = __builtin_amdgcn_mfma_f32_16x16x32_f16(wa[q][3], bf3, acc[q], 0, 0, 0); \
            }                                                                  \
            half4 hh;                                                          \
            ACT(0) ACT(1) ACT(2) ACT(3)                                        \
            *(half4*)&A2[1 - (P)][ln][64 + ub] = hh;                           \
        }                                                                      \
        sync_lds();                                                            \
    } while (0)

    for (int jj = 0; jj < T_STEPS; jj += 2) {
        STEP(jj, 0);
        STEP(jj + 1, 1);
    }
    STEP(T_STEPS, 0);   // drain: layer 2 computes h2(255) -> A2[1]

    // ---- output head: out[b] = h2(255) . Wout + bout ----
    if (tid < NB) {
        float s = bout[0];
        #pragma unroll 8
        for (int u = 0; u < 64; ++u)
            s += (float)A2[1][tid][64 + u] * Wout[u];
        out[gb0 + tid] = s;
    }
}

extern "C" void kernel_launch(void* const* d_in, const int* in_sizes, int n_in,
                              void* d_out, int out_size, void* d_ws, size_t ws_size,
                              hipStream_t stream) {
    const float* x    = (const float*)d_in[0];
    const float* Wih0 = (const float*)d_in[1];
    const float* Whh0 = (const float*)d_in[2];
    const float* bih0 = (const float*)d_in[3];
    const float* bhh0 = (const float*)d_in[4];
    const float* Wih1 = (const float*)d_in[5];
    const float* Whh1 = (const float*)d_in[6];
    const float* bih1 = (const float*)d_in[7];
    const float* bhh1 = (const float*)d_in[8];
    const float* Wout = (const float*)d_in[9];
    const float* bout = (const float*)d_in[10];

    hipLaunchKernelGGL(lstm_pipe8, dim3(NBLOCKS), dim3(512), 0, stream,
                       x, Wih0, Whh0, bih0, bhh0,
                       Wih1, Whh1, bih1, bhh1, Wout, bout,
                       (float*)d_out);
}

// Round 5
// 174.225 us; speedup vs baseline: 13.0296x; 1.0614x over previous
//
#include <hip/hip_runtime.h>

typedef _Float16 half8 __attribute__((ext_vector_type(8)));
typedef _Float16 half4 __attribute__((ext_vector_type(4)));
typedef float f32x4 __attribute__((ext_vector_type(4)));

#define T_STEPS 256
#define NB      16
#define NBLOCKS (4096/NB)
#define LOG2E   1.4426950408889634f

// merged activation buffer stride (f16 units): cols 0..63 = h1, 64..127 = h2.
// 136 = 8*17 -> b128 reads: chunk slot (17*ln+lb)%8 = (ln+lb)%8 uniform;
// b64 writes: (68*ln+8*wq+2*lb)%32 uniform -> no bank conflicts.
#define SH 136

__device__ __forceinline__ half8 cvt8s(const float* __restrict__ p, float s) {
    half8 r;
    #pragma unroll
    for (int j = 0; j < 8; ++j) r[j] = (_Float16)(p[j] * s);
    return r;
}

// LDS-only barrier: does NOT drain vmcnt, so global x prefetch stays in flight.
__device__ __forceinline__ void sync_lds() {
    asm volatile("s_waitcnt lgkmcnt(0)" ::: "memory");
    __builtin_amdgcn_s_barrier();
}

__global__ __launch_bounds__(512, 1)
void lstm_v5(const float* __restrict__ x,
             const float* __restrict__ Wih0, const float* __restrict__ Whh0,
             const float* __restrict__ bih0, const float* __restrict__ bhh0,
             const float* __restrict__ Wih1, const float* __restrict__ Whh1,
             const float* __restrict__ bih1, const float* __restrict__ bhh1,
             const float* __restrict__ Wout, const float* __restrict__ bout,
             float* __restrict__ out)
{
    __shared__ _Float16 Hb[2][16][SH];

    const int tid  = threadIdx.x;
    const int w    = tid >> 6;
    const bool isL1 = (w < 4);          // waves 0-3: layer 1; waves 4-7: layer 2
    const int wq   = w & 3;
    const int l    = tid & 63;
    const int ln   = l & 15;            // weight row (A) / batch col (B)
    const int lb   = l >> 4;            // k sub-block / C-row group
    const int ub   = 16 * wq + 4 * lb;  // first unit this lane's acc covers
    const int gb0  = blockIdx.x * NB;

    // ---- weight A-fragments, register-resident, sign/scale pre-folded ----
    // gate q scale: i,f,o -> -log2e (so exp2(acc) = e^{-raw}); g -> +2*log2e
    // (so exp2(acc) = e^{2*raw}).
    half8 wa[4][4];   // L1 uses [q][0..1] (h1 part), L2 uses [q][0..3]
    half8 wax[4];     // L1 only: x part (K=32)
    f32x4 bv[4];
    if (isL1) {
        #pragma unroll
        for (int q = 0; q < 4; ++q) {
            const float s = (q == 2) ? 2.f * LOG2E : -LOG2E;
            const int g = 64 * q + 16 * wq + ln;
            wax[q] = cvt8s(Wih0 + g * 32 + 8 * lb, s);
            #pragma unroll
            for (int ks = 0; ks < 2; ++ks)
                wa[q][ks] = cvt8s(Whh0 + g * 64 + 32 * ks + 8 * lb, s);
            #pragma unroll
            for (int jj = 0; jj < 4; ++jj) {
                const int gj = 64 * q + ub + jj;
                bv[q][jj] = (bih0[gj] + bhh0[gj]) * s;
            }
        }
    } else {
        #pragma unroll
        for (int q = 0; q < 4; ++q) {
            const float s = (q == 2) ? 2.f * LOG2E : -LOG2E;
            const int g = 64 * q + 16 * wq + ln;
            #pragma unroll
            for (int ks = 0; ks < 4; ++ks) {
                const int c0 = 32 * ks + 8 * lb;
                const float* p = (c0 < 64) ? (Wih1 + g * 64 + c0)
                                           : (Whh1 + g * 64 + (c0 - 64));
                wa[q][ks] = cvt8s(p, s);
            }
            #pragma unroll
            for (int jj = 0; jj < 4; ++jj) {
                const int gj = 64 * q + ub + jj;
                bv[q][jj] = (bih1[gj] + bhh1[gj]) * s;
            }
        }
    }

    float cst[4] = {0.f, 0.f, 0.f, 0.f};

    // ---- zero LDS (h1(-1)=h2(-1)=h2(-2)=0) ----
    {
        unsigned int* z = (unsigned int*)Hb;
        for (int i = tid; i < (int)(sizeof(Hb) / 4); i += 512) z[i] = 0u;
    }

    // ---- L1 x pipeline: lane (ln,lb) owns x[gb0+ln][t][8lb..8lb+7] ----
    const float* xb = x + (long)(gb0 + ln) * T_STEPS * 32 + 8 * lb;
    f32x4 xr0 = {0.f,0.f,0.f,0.f}, xr1 = {0.f,0.f,0.f,0.f};
    f32x4 gxA[4], gxB[4];
    if (isL1) {
        // gx(0) = bias + W_x @ x(0)
        xr0 = *(const f32x4*)(xb);
        xr1 = *(const f32x4*)(xb + 4);
        half8 xf;
        #pragma unroll
        for (int j = 0; j < 4; ++j) { xf[j] = (_Float16)xr0[j]; xf[4+j] = (_Float16)xr1[j]; }
        #pragma unroll
        for (int q = 0; q < 4; ++q) {
            gxA[q] = bv[q];
            gxA[q] = __builtin_amdgcn_mfma_f32_16x16x32_f16(wax[q], xf, gxA[q], 0, 0, 0);
        }
        xr0 = *(const f32x4*)(xb + 32);      // x(1)
        xr1 = *(const f32x4*)(xb + 36);
    }
    sync_lds();

// LSTM cell update, weights pre-scaled: ei=e^{-i}, ef=e^{-f}, Eg=e^{2g}, eo=e^{-o}
// c' = [c*(1+ei)(1+Eg) + (Eg-1)(1+ef)] / ((1+ei)(1+Eg)(1+ef))
// h  = (Ec-1) / ((1+eo)(1+Ec)),  Ec = e^{2c'}
#define ACT1(A, JJ)                                                            \
    {                                                                          \
        const float ei = __builtin_amdgcn_exp2f(A[0][JJ]);                     \
        const float ef = __builtin_amdgcn_exp2f(A[1][JJ]);                     \
        const float Eg = __builtin_amdgcn_exp2f(A[2][JJ]);                     \
        const float eo = __builtin_amdgcn_exp2f(A[3][JJ]);                     \
        const float ti = 1.f + ei, tf = 1.f + ef, tg = 1.f + Eg;               \
        const float pig = ti * tg;                                             \
        const float num = fmaf(Eg - 1.f, tf, cst[JJ] * pig);                   \
        const float c   = num * __builtin_amdgcn_rcpf(pig * tf);               \
        cst[JJ] = c;                                                           \
        const float Ec  = __builtin_amdgcn_exp2f(fminf((2.f * LOG2E) * c, 120.f)); \
        hh[JJ] = (_Float16)((Ec - 1.f) *                                       \
                 __builtin_amdgcn_rcpf((1.f + eo) * (1.f + Ec)));              \
    }

#define STEP(J, P, GXC, GXN)                                                   \
    do {                                                                       \
        if (isL1 && (J) < T_STEPS) {                                           \
            /* issue h1(J-1) reads first */                                    \
            const half8 bf0 = *(const half8*)&Hb[P][ln][8 * lb];               \
            const half8 bf1 = *(const half8*)&Hb[P][ln][32 + 8 * lb];          \
            /* cover read latency: build gx(J+1) from registers */             \
            half8 xf;                                                          \
            _Pragma("unroll")                                                  \
            for (int j = 0; j < 4; ++j) { xf[j] = (_Float16)xr0[j]; xf[4+j] = (_Float16)xr1[j]; } \
            _Pragma("unroll")                                                  \
            for (int q = 0; q < 4; ++q) GXN[q] = bv[q];                        \
            _Pragma("unroll")                                                  \
            for (int q = 0; q < 4; ++q)                                        \
                GXN[q] = __builtin_amdgcn_mfma_f32_16x16x32_f16(wax[q], xf, GXN[q], 0, 0, 0); \
            /* prefetch x(J+2); vmcnt never drained at barrier */              \
            { const int jn = ((J) + 2 < T_STEPS) ? (J) + 2 : T_STEPS - 1;      \
              xr0 = *(const f32x4*)(xb + jn * 32);                             \
              xr1 = *(const f32x4*)(xb + jn * 32 + 4); }                       \
            /* layer 1 recurrent part */                                       \
            __builtin_amdgcn_s_setprio(1);                                     \
            _Pragma("unroll")                                                  \
            for (int q = 0; q < 4; ++q) {                                      \
                GXC[q] = __builtin_amdgcn_mfma_f32_16x16x32_f16(wa[q][0], bf0, GXC[q], 0, 0, 0); \
                GXC[q] = __builtin_amdgcn_mfma_f32_16x16x32_f16(wa[q][1], bf1, GXC[q], 0, 0, 0); \
            }                                                                  \
            __builtin_amdgcn_s_setprio(0);                                     \
            half4 hh;                                                          \
            ACT1(GXC, 0) ACT1(GXC, 1) ACT1(GXC, 2) ACT1(GXC, 3)                \
            *(half4*)&Hb[1 - (P)][ln][ub] = hh;                                \
        }                                                                      \
        if (!isL1 && (J) > 0) {                                                \
            const half8 bf0 = *(const half8*)&Hb[P][ln][8 * lb];               \
            const half8 bf1 = *(const half8*)&Hb[P][ln][32 + 8 * lb];          \
            const half8 bf2 = *(const half8*)&Hb[P][ln][64 + 8 * lb];          \
            const half8 bf3 = *(const half8*)&Hb[P][ln][96 + 8 * lb];          \
            f32x4 acc[4];                                                      \
            _Pragma("unroll")                                                  \
            for (int q = 0; q < 4; ++q) acc[q] = bv[q];                        \
            __builtin_amdgcn_s_setprio(1);                                     \
            _Pragma("unroll")                                                  \
            for (int q = 0; q < 4; ++q) {                                      \
                acc[q] = __builtin_amdgcn_mfma_f32_16x16x32_f16(wa[q][0], bf0, acc[q], 0, 0, 0); \
                acc[q] = __builtin_amdgcn_mfma_f32_16x16x32_f16(wa[q][1], bf1, acc[q], 0, 0, 0); \
                acc[q] = __builtin_amdgcn_mfma_f32_16x16x32_f16(wa[q][2], bf2, acc[q], 0, 0, 0); \
                acc[q] = __builtin_amdgcn_mfma_f32_16x16x32_f16(wa[q][3], bf3, acc[q], 0, 0, 0); \
            }                                                                  \
            __builtin_amdgcn_s_setprio(0);                                     \
            half4 hh;                                                          \
            ACT1(acc, 0) ACT1(acc, 1) ACT1(acc, 2) ACT1(acc, 3)                \
            *(half4*)&Hb[1 - (P)][ln][64 + ub] = hh;                           \
        }                                                                      \
        sync_lds();                                                            \
    } while (0)

    for (int jj = 0; jj < T_STEPS; jj += 2) {
        STEP(jj, 0, gxA, gxB);
        STEP(jj + 1, 1, gxB, gxA);
    }
    STEP(T_STEPS, 0, gxA, gxB);   // drain: layer 2 computes h2(255) -> Hb[1]

    // ---- output head: out[b] = h2(255) . Wout + bout ----
    if (tid < NB) {
        float s = bout[0];
        #pragma unroll
        for (int u8 = 0; u8 < 8; ++u8) {
            const half8 hv = *(const half8*)&Hb[1][tid][64 + 8 * u8];
            #pragma unroll
            for (int j = 0; j < 8; ++j)
                s += (float)hv[j] * Wout[8 * u8 + j];
        }
        out[gb0 + tid] = s;
    }
}

extern "C" void kernel_launch(void* const* d_in, const int* in_sizes, int n_in,
                              void* d_out, int out_size, void* d_ws, size_t ws_size,
                              hipStream_t stream) {
    const float* x    = (const float*)d_in[0];
    const float* Wih0 = (const float*)d_in[1];
    const float* Whh0 = (const float*)d_in[2];
    const float* bih0 = (const float*)d_in[3];
    const float* bhh0 = (const float*)d_in[4];
    const float* Wih1 = (const float*)d_in[5];
    const float* Whh1 = (const float*)d_in[6];
    const float* bih1 = (const float*)d_in[7];
    const float* bhh1 = (const float*)d_in[8];
    const float* Wout = (const float*)d_in[9];
    const float* bout = (const float*)d_in[10];

    hipLaunchKernelGGL(lstm_v5, dim3(NBLOCKS), dim3(512), 0, stream,
                       x, Wih0, Whh0, bih0, bhh0,
                       Wih1, Whh1, bih1, bhh1, Wout, bout,
                       (float*)d_out);
}